// Round 9
// baseline (221.334 us; speedup 1.0000x reference)
//
#include <hip/hip_runtime.h>
#include <math.h>

#define N_NODES 25000
#define N_EDGES 400000
#define EMBED   128
#define HEADS   8
#define DK      16
#define NBLK    98        // ceil(25000/256)

typedef __attribute__((ext_vector_type(8))) short bf16x8;
typedef __attribute__((ext_vector_type(4))) float f32x4;
typedef unsigned int uint;
typedef unsigned short ushort;

__device__ inline uint pack2_bf16(float a, float b) {
    union { float f; uint u; } ua, ub;
    ua.f = a; ub.f = b;
    uint ra = (ua.u + 0x7FFFu + ((ua.u >> 16) & 1u)) >> 16;
    uint rb = (ub.u + 0x7FFFu + ((ub.u >> 16) & 1u)) >> 16;
    return (ra & 0xFFFFu) | (rb << 16);
}
__device__ inline ushort cvt_bf16(float a) {
    union { float f; uint u; } ua; ua.f = a;
    return (ushort)((ua.u + 0x7FFFu + ((ua.u >> 16) & 1u)) >> 16);
}
__device__ inline float bf16_lo(uint u) {
    union { uint u; float f; } x; x.u = u << 16; return x.f;
}
__device__ inline float bf16_hi(uint u) {
    union { uint u; float f; } x; x.u = u & 0xFFFF0000u; return x.f;
}

// ---------------------------------------------------------------------------
// Convert the four 128x128 weights to bf16 (32768 uint pairs); zero deg.
// ---------------------------------------------------------------------------
#define NX (N_NODES * 128)
__global__ __launch_bounds__(256) void convert_w_deg(
    const float* __restrict__ Wq, const float* __restrict__ Wk,
    const float* __restrict__ Wv, const float* __restrict__ Wo,
    ushort* __restrict__ wb, int* __restrict__ deg)
{
    int i = blockIdx.x * 256 + threadIdx.x;   // pair index
    if (i < N_NODES) deg[i] = 0;
    if (i < 32768) {
        int j = i * 2;
        const float* src = (j < 16384) ? Wq + j
                         : (j < 32768) ? Wk + (j - 16384)
                         : (j < 49152) ? Wv + (j - 32768)
                         :               Wo + (j - 49152);
        float2 v = *reinterpret_cast<const float2*>(src);
        reinterpret_cast<uint*>(wb)[i] = pack2_bf16(v.x, v.y);
    }
}

// ---------------------------------------------------------------------------
// MFMA GEMM for Q/K/V + degree histogram.
// blockIdx.y in {0,1,2}: GEMM with weights/bias q/k/v; y==3: histogram.
// A is fp32 x, packed to bf16 inline (saves the xb convert pass).
// Outputs row-major bf16 [row*128+col].
// ---------------------------------------------------------------------------
__global__ __launch_bounds__(256) void gemm_qkv_deg(
    const float* __restrict__ x, const ushort* __restrict__ Wall,
    const float* __restrict__ bq, const float* __restrict__ bk,
    const float* __restrict__ bv,
    ushort* __restrict__ Qb, ushort* __restrict__ Kb, ushort* __restrict__ Vb,
    const int* __restrict__ ei, int* __restrict__ deg,
    int M)
{
    const int which = blockIdx.y;
    if (which == 3) {
        int t = blockIdx.x * 256 + threadIdx.x;
        int e = t * 4;
        if (e + 3 < N_EDGES) {
            int4 d = *reinterpret_cast<const int4*>(ei + e);
            atomicAdd(&deg[d.x], 1);
            atomicAdd(&deg[d.y], 1);
            atomicAdd(&deg[d.z], 1);
            atomicAdd(&deg[d.w], 1);
        } else {
            for (; e < N_EDGES && e < t * 4 + 4; ++e)
                atomicAdd(&deg[ei[e]], 1);
        }
        return;
    }

    const ushort* W = Wall + which * 16384;
    const float* bias = (which == 0) ? bq : (which == 1) ? bk : bv;
    ushort* C = (which == 0) ? Qb : (which == 1) ? Kb : Vb;

    const int lane = threadIdx.x & 63;
    const int wave = threadIdx.x >> 6;
    const int ml   = lane & 15;
    const int quad = lane >> 4;
    const int m0   = blockIdx.x * 64 + wave * 16;

    int arow = m0 + ml; if (arow >= M) arow = M - 1;
    const float4* xf4 = reinterpret_cast<const float4*>(x) + arow * 32 + quad * 2;

    f32x4 acc[8];
#pragma unroll
    for (int ct = 0; ct < 8; ++ct) acc[ct] = (f32x4){0.f, 0.f, 0.f, 0.f};

#pragma unroll
    for (int ks = 0; ks < 128; ks += 32) {
        float4 f0 = xf4[ks >> 2];
        float4 f1 = xf4[(ks >> 2) + 1];
        bf16x8 af;
        {
            uint* au = reinterpret_cast<uint*>(&af);
            au[0] = pack2_bf16(f0.x, f0.y);
            au[1] = pack2_bf16(f0.z, f0.w);
            au[2] = pack2_bf16(f1.x, f1.y);
            au[3] = pack2_bf16(f1.z, f1.w);
        }
#pragma unroll
        for (int ct = 0; ct < 8; ++ct) {
            bf16x8 bf = *reinterpret_cast<const bf16x8*>(
                W + (ct * 16 + ml) * 128 + ks + quad * 8);
            acc[ct] = __builtin_amdgcn_mfma_f32_16x16x32_bf16(af, bf, acc[ct], 0, 0, 0);
        }
    }

#pragma unroll
    for (int ct = 0; ct < 8; ++ct) {
        int col = ct * 16 + ml;
        float bv_ = bias[col];
#pragma unroll
        for (int r = 0; r < 4; ++r) {
            int row = m0 + quad * 4 + r;
            if (row < M)
                C[row * 128 + col] = cvt_bf16(acc[ct][r] + bv_);
        }
    }
}

// Final projection: A bf16 [M,128] @ W^T + bias -> fp32 out
__global__ __launch_bounds__(256) void gemm_out(
    const ushort* __restrict__ A, const ushort* __restrict__ W,
    const float* __restrict__ bias, float* __restrict__ C, int M)
{
    const int lane = threadIdx.x & 63;
    const int wave = threadIdx.x >> 6;
    const int ml   = lane & 15;
    const int quad = lane >> 4;
    const int m0   = blockIdx.x * 64 + wave * 16;

    int arow = m0 + ml; if (arow >= M) arow = M - 1;
    const ushort* ap = A + arow * 128 + quad * 8;

    f32x4 acc[8];
#pragma unroll
    for (int ct = 0; ct < 8; ++ct) acc[ct] = (f32x4){0.f, 0.f, 0.f, 0.f};

#pragma unroll
    for (int ks = 0; ks < 128; ks += 32) {
        bf16x8 af = *reinterpret_cast<const bf16x8*>(ap + ks);
#pragma unroll
        for (int ct = 0; ct < 8; ++ct) {
            bf16x8 bf = *reinterpret_cast<const bf16x8*>(
                W + (ct * 16 + ml) * 128 + ks + quad * 8);
            acc[ct] = __builtin_amdgcn_mfma_f32_16x16x32_bf16(af, bf, acc[ct], 0, 0, 0);
        }
    }

#pragma unroll
    for (int ct = 0; ct < 8; ++ct) {
        int col = ct * 16 + ml;
        float bv_ = bias[col];
#pragma unroll
        for (int r = 0; r < 4; ++r) {
            int row = m0 + quad * 4 + r;
            if (row < M)
                C[row * 128 + col] = acc[ct][r] + bv_;
        }
    }
}

// ---------------------------------------------------------------------------
// Hierarchical exclusive scan (2 kernels: per-block scan, then apply with
// inline top-level scan) + scatter (int2 {e, src}).
// ---------------------------------------------------------------------------
__global__ __launch_bounds__(256) void scan_blocks(
    const int* __restrict__ deg, int* __restrict__ excl, int* __restrict__ bsum)
{
    __shared__ int sh[256];
    int t = threadIdx.x;
    int gid = blockIdx.x * 256 + t;
    int v = (gid < N_NODES) ? deg[gid] : 0;
    sh[t] = v;
    __syncthreads();
#pragma unroll
    for (int off = 1; off < 256; off <<= 1) {
        int u = (t >= off) ? sh[t - off] : 0;
        __syncthreads();
        sh[t] += u;
        __syncthreads();
    }
    if (gid < N_NODES) excl[gid] = sh[t] - v;
    if (t == 255) bsum[blockIdx.x] = sh[255];
}

// apply block bases (inline prefix over <=98 block sums) -> offsets + cursor
__global__ __launch_bounds__(256) void scan_apply(
    int* __restrict__ excl, const int* __restrict__ bsum,
    int* __restrict__ cursor)
{
    __shared__ int base_sh;
    int t = threadIdx.x;
    if (t < 64) {
        int s = 0;
        for (int i = t; i < (int)blockIdx.x; i += 64) s += bsum[i];
#pragma unroll
        for (int off = 32; off; off >>= 1) s += __shfl_xor(s, off, 64);
        if (t == 0) base_sh = s;
    }
    __syncthreads();
    int gid = blockIdx.x * 256 + t;
    if (gid < N_NODES) {
        int o = excl[gid] + base_sh;
        excl[gid] = o;         // excl buffer IS offsets
        cursor[gid] = o;
    }
    if (blockIdx.x == 0 && t == 0) excl[N_NODES] = N_EDGES;
}

__global__ __launch_bounds__(256) void scatter_edges(
    const int* __restrict__ ei, int* __restrict__ cursor,
    int2* __restrict__ csr2)
{
    int e = blockIdx.x * 256 + threadIdx.x;
    if (e >= N_EDGES) return;
    int dst = ei[e];
    int src = ei[N_EDGES + e];
    int pos = atomicAdd(&cursor[dst], 1);
    csr2[pos] = make_int2(e, src);
}

// ---------------------------------------------------------------------------
// Fused attention v8: one wave per node, one (edge, head) per lane,
// SIXTEEN edges in flight (two 8-edge groups per iteration -> 8 independent
// uint4 K/V loads per lane). lane = e_slot*8 + h. Full 16-dim dot in
// registers; exp once per (e,h); reduce-scatter butterfly at the end.
// exp without max-subtraction (identical softmax; logits are O(+-10)).
// ---------------------------------------------------------------------------
__device__ inline float dot16(const float* qf, uint4 a, uint4 b) {
    float d = 0.f;
    d += qf[0]  * bf16_lo(a.x) + qf[1]  * bf16_hi(a.x);
    d += qf[2]  * bf16_lo(a.y) + qf[3]  * bf16_hi(a.y);
    d += qf[4]  * bf16_lo(a.z) + qf[5]  * bf16_hi(a.z);
    d += qf[6]  * bf16_lo(a.w) + qf[7]  * bf16_hi(a.w);
    d += qf[8]  * bf16_lo(b.x) + qf[9]  * bf16_hi(b.x);
    d += qf[10] * bf16_lo(b.y) + qf[11] * bf16_hi(b.y);
    d += qf[12] * bf16_lo(b.z) + qf[13] * bf16_hi(b.z);
    d += qf[14] * bf16_lo(b.w) + qf[15] * bf16_hi(b.w);
    return d;
}

__global__ __launch_bounds__(256) void fused_attn(
    const ushort* __restrict__ Q2, const ushort* __restrict__ K2,
    const ushort* __restrict__ V2,
    const float* __restrict__ attn_bias,
    const int* __restrict__ offsets, const int2* __restrict__ csr2,
    float* __restrict__ logits, ushort* __restrict__ AGG)
{
    const int lane = threadIdx.x & 63;
    const int wid  = threadIdx.x >> 6;
    const int n = blockIdx.x * 4 + wid;
    const int start = offsets[n], end = offsets[n + 1];
    const int h  = lane & 7;
    const int es = lane >> 3;

    const uint4* Qu4 = reinterpret_cast<const uint4*>(Q2);
    const uint4* Ku4 = reinterpret_cast<const uint4*>(K2);
    const uint4* Vu4 = reinterpret_cast<const uint4*>(V2);

    uint4 qa = Qu4[n * 16 + h * 2];
    uint4 qb = Qu4[n * 16 + h * 2 + 1];
    float qf[16];
    {
        uint qq[8] = {qa.x, qa.y, qa.z, qa.w, qb.x, qb.y, qb.z, qb.w};
#pragma unroll
        for (int j = 0; j < 8; ++j) {
            qf[2 * j]     = bf16_lo(qq[j]);
            qf[2 * j + 1] = bf16_hi(qq[j]);
        }
    }

    float acc[16];
#pragma unroll
    for (int j = 0; j < 16; ++j) acc[j] = 0.f;
    float z = 0.f;

    for (int base = start; base < end; base += 16) {
        int i0 = base + es;     bool ok0 = i0 < end; if (!ok0) i0 = start;
        int i1 = base + 8 + es; bool ok1 = i1 < end; if (!ok1) i1 = start;
        int2 p0 = csr2[i0];
        int2 p1 = csr2[i1];

        uint4 k00 = Ku4[p0.y * 16 + h * 2], k01 = Ku4[p0.y * 16 + h * 2 + 1];
        uint4 k10 = Ku4[p1.y * 16 + h * 2], k11 = Ku4[p1.y * 16 + h * 2 + 1];
        uint4 v00 = Vu4[p0.y * 16 + h * 2], v01 = Vu4[p0.y * 16 + h * 2 + 1];
        uint4 v10 = Vu4[p1.y * 16 + h * 2], v11 = Vu4[p1.y * 16 + h * 2 + 1];
        float b0 = attn_bias[p0.x * 8 + h];
        float b1 = attn_bias[p1.x * 8 + h];

        float d0 = dot16(qf, k00, k01);
        float d1 = dot16(qf, k10, k11);
        float l0 = 0.25f * d0 + b0;
        float l1 = 0.25f * d1 + b1;

        float pe0 = 0.f, pe1 = 0.f;
        if (ok0) { logits[p0.x * 8 + h] = l0; pe0 = __expf(l0); }
        if (ok1) { logits[p1.x * 8 + h] = l1; pe1 = __expf(l1); }
        z += pe0 + pe1;

        uint w0[8] = {v00.x, v00.y, v00.z, v00.w, v01.x, v01.y, v01.z, v01.w};
        uint w1[8] = {v10.x, v10.y, v10.z, v10.w, v11.x, v11.y, v11.z, v11.w};
#pragma unroll
        for (int j = 0; j < 8; ++j) {
            acc[2 * j]     += pe0 * bf16_lo(w0[j]) + pe1 * bf16_lo(w1[j]);
            acc[2 * j + 1] += pe0 * bf16_hi(w0[j]) + pe1 * bf16_hi(w1[j]);
        }
    }

    // reduce-scatter butterfly over e_slot bits (lane bits 5,4,3)
    {
        int bit = (lane >> 5) & 1;
#pragma unroll
        for (int j = 0; j < 8; ++j) {
            float send = bit ? acc[j] : acc[j + 8];
            float keep = bit ? acc[j + 8] : acc[j];
            acc[j] = keep + __shfl_xor(send, 32, 64);
        }
        bit = (lane >> 4) & 1;
#pragma unroll
        for (int j = 0; j < 4; ++j) {
            float send = bit ? acc[j] : acc[j + 4];
            float keep = bit ? acc[j + 4] : acc[j];
            acc[j] = keep + __shfl_xor(send, 16, 64);
        }
        bit = (lane >> 3) & 1;
#pragma unroll
        for (int j = 0; j < 2; ++j) {
            float send = bit ? acc[j] : acc[j + 2];
            float keep = bit ? acc[j + 2] : acc[j];
            acc[j] = keep + __shfl_xor(send, 8, 64);
        }
    }
    z += __shfl_xor(z, 8, 64);
    z += __shfl_xor(z, 16, 64);
    z += __shfl_xor(z, 32, 64);

    float inv = (z > 0.f) ? 1.f / z : 0.f;
    int d_off = ((lane >> 5) & 1) * 8 + ((lane >> 4) & 1) * 4 + ((lane >> 3) & 1) * 2;
    reinterpret_cast<uint*>(AGG)[n * 64 + h * 8 + (d_off >> 1)] =
        pack2_bf16(acc[0] * inv, acc[1] * inv);
}

// ---------------------------------------------------------------------------
extern "C" void kernel_launch(void* const* d_in, const int* in_sizes, int n_in,
                              void* d_out, int out_size, void* d_ws, size_t ws_size,
                              hipStream_t stream)
{
    const float* x         = (const float*)d_in[0];
    const int*   ei        = (const int*)  d_in[1];
    const float* attn_bias = (const float*)d_in[2];
    const float* Wq = (const float*)d_in[3];
    const float* bq = (const float*)d_in[4];
    const float* Wk = (const float*)d_in[5];
    const float* bk = (const float*)d_in[6];
    const float* Wv = (const float*)d_in[7];
    const float* bv = (const float*)d_in[8];
    const float* Wo = (const float*)d_in[9];
    const float* bo = (const float*)d_in[10];

    float* out    = (float*)d_out;                // [N,128]
    float* logits = out + N_NODES * EMBED;        // [E,8] (output 1)

    ushort* wb   = (ushort*)d_ws;                 // 4*16384 (Wq,Wk,Wv,Wo)
    ushort* Qb   = wb + 4 * 16384;                // N*128
    ushort* Kb   = Qb + NX;                       // N*128
    ushort* Vb   = Kb + NX;                       // N*128
    ushort* AGGb = Vb + NX;                       // N*128
    int* deg     = (int*)(AGGb + NX);
    int* offsets = deg + N_NODES;                 // N+1 (also excl buffer)
    int* cursor  = offsets + N_NODES + 1;
    int2* csr2   = (int2*)(cursor + N_NODES);     // E pairs {edge, src}
    int* bsum    = (int*)(csr2 + N_EDGES);        // NBLK

    convert_w_deg<<<128, 256, 0, stream>>>(Wq, Wk, Wv, Wo, wb, deg);

    int gblocks = (N_NODES + 63) / 64;            // 391
    dim3 qkvgrid(gblocks, 4);                     // y=0..2 gemm, y=3 histogram
    gemm_qkv_deg<<<qkvgrid, 256, 0, stream>>>(x, wb, bq, bk, bv, Qb, Kb, Vb,
                                              ei, deg, N_NODES);

    scan_blocks<<<NBLK, 256, 0, stream>>>(deg, offsets, bsum);
    scan_apply<<<NBLK, 256, 0, stream>>>(offsets, bsum, cursor);
    scatter_edges<<<(N_EDGES + 255) / 256, 256, 0, stream>>>(ei, cursor, csr2);

    fused_attn<<<N_NODES / 4, 256, 0, stream>>>(Qb, Kb, Vb, attn_bias,
                                                offsets, csr2, logits, AGGb);

    gemm_out<<<gblocks, 256, 0, stream>>>(AGGb, wb + 3 * 16384, bo, out, N_NODES);
}